// Round 6
// baseline (654.483 us; speedup 1.0000x reference)
//
#include <hip/hip_runtime.h>

// SimpleRNN: h_{t+1} = tanh(h_t @ H^T + x_t @ U + b); out = h_T @ A^T + c
// T=512 B=2048 IN=28 HID=198 OUT=10, fp32 in/out, fp16 recurrence.
//
// R14 = R13 with __launch_bounds__ fixed (512,4 -> 512,2).
// R13 (458us) FAILED on register spill, not on the interleave thesis:
// VGPR_Count=64 vs ~115 demand -> WRITE_SIZE exploded 80KB -> 25.7MB
// (scratch spill-stores) + FETCH +21MB (reloads). The (512,4) bound
// behaved as 4 blocks/CU (CUDA minBlocks semantics) -> 32 waves/CU ->
// 64-VGPR cap. (512,2) -> 2 blocks/CU -> 128-VGPR cap; demand ~115 fits,
// 2 blocks co-resident. MfmaUtil 31.6->42 / VALUBusy 35.8->45 in R13
// show the cross-block phase interleave engaging even while spilling.
//
// Structure (R13): phase-interleave via 2 independent blocks/CU.
// R12 (306us, step 1434cyc) killed bank conflicts (27.3M->538K) with ZERO
// time change -> LDS occupancy not binding; pipes serialize because all
// 16 waves are barrier-locked into the same phase (LDS burst ~624 + VALU
// ~513 + MFMA ~450 ~= step). grid=512, BB=4, 8 waves/block, 2 blocks/CU
// (16 waves/CU = 4/SIMD, R9 lesson preserved). Blocks share no barrier ->
// block A's MFMA/tanh overlaps block B's LDS burst.
//
// Layout (diagonal k-half MFMA, BB=4): A rows 0-7 = (b=0..3 x khalf),
// rows 8-15 duplicate (2-way same-address LDS broadcast = free, m136).
//   row m: b=(m&7)>>1, khalf=m&1. B cols 0-7 = 8 j's @ k-lo, 8-15 same @ k-hi.
// C[4q+r][n16]: lane keeps r0 (lo) / r3 (hi), partner (lane^8) supplies
// r1/r2 via ONE full-EXEC row_ror:8 (R10 lesson: no convergent op under
// divergent control). acc init {bias,0,0,bias} -> bias lands exactly once.
// Quads 0-1 own outputs (b = 2q + hi); quads 2-3 are duplicates, writes
// suppressed. 7 compute waves x {4,4,4,4,3,3,3} groups = 25 groups of 8
// cols (>=198; phantom j guarded). Per wave: 4 ds_read_b128 (shared by all
// its groups) + 4*ng MFMAs in ng independent 4-chains.
// K layout: k 0..197 = H, 224..251 = x (tau3 khi slots), gaps zero forever.
// Stager: wave 7 lanes 0-15 (b=lane>>2, kq=lane&3), depth-2 reg pipeline
// (load x[t+3] during t, commit at t+2).

#define T_STEPS 512
#define BATCH   2048
#define IN_DIM  28
#define HID     198
#define OUT_DIM 10
#define BB      4      // batch rows per block
#define NTAU    4      // K-tiles of 64
#define NTHREADS 512   // 8 waves
#define NGMAX   4

typedef __attribute__((ext_vector_type(8))) _Float16 half8;
typedef __attribute__((ext_vector_type(4))) float   floatx4;

__device__ __forceinline__ floatx4 mfma16(half8 a, half8 b, floatx4 c) {
    return __builtin_amdgcn_mfma_f32_16x16x32_f16(a, b, c, 0, 0, 0);
}

// tanh(x) = 1 - 2/(exp(2x)+1); exp2-based, saturates via IEEE inf/0.
__device__ __forceinline__ float fast_tanh(float x) {
    float e = __builtin_amdgcn_exp2f(x * 2.885390081777926357f); // exp(2x)
    float r = __builtin_amdgcn_rcpf(e + 1.0f);
    return __builtin_fmaf(-2.0f, r, 1.0f);
}

// lane <- lane^8 within each 16-lane DPP row. Full-EXEC straight-line only.
__device__ __forceinline__ float ror8(float v) {
    return __builtin_bit_cast(float,
        __builtin_amdgcn_mov_dpp(__builtin_bit_cast(int, v),
                                 0x128 /*row_ror:8*/, 0xf, 0xf, true));
}

__global__ void __launch_bounds__(NTHREADS, 2)   // 2 blocks/CU, 128-VGPR cap
rnn_kernel(const float* __restrict__ x, const float* __restrict__ H,
           const float* __restrict__ U, const float* __restrict__ A,
           const float* __restrict__ bvec, const float* __restrict__ cvec,
           float* __restrict__ out)
{
    // [buf][tau][slot][idx] fp16; slot(b,khalf,kq) = kq*8 + b*2 + khalf.
    // Lane (n16,q) reads b128 at slot q*8 + (n16&7): per 16-lane phase,
    // 8 unique slots (banks 0-31 exactly once) + 8 same-addr duplicates.
    __shared__ __align__(16) _Float16 lds_A[2][NTAU][32][8];   // 4 KB
    __shared__ float lds_h[BB][204];                            // final h

    const int tid  = threadIdx.x;
    const int lane = tid & 63;
    const int wv   = tid >> 6;          // wave id 0..7
    const int n16  = lane & 15;
    const int q    = lane >> 4;         // 0..3
    const int jl   = n16 & 7;
    const int b0   = blockIdx.x * BB;

    // zero-init both buffers (h0 = 0; phantom K slots stay 0 forever)
    {
        _Float16* p0 = &lds_A[0][0][0][0];
        for (int i = tid; i < 2*NTAU*32*8; i += NTHREADS) p0[i] = (_Float16)0.0f;
    }

    const floatx4 zero4 = {0.0f, 0.0f, 0.0f, 0.0f};
    const bool is_cw = (wv < 7);

    const int aslot = q*8 + (n16 & 7);

    // group assignment: waves 0-3 -> 4 groups, waves 4-6 -> 3 groups (25 total)
    const int ng    = (wv < 4) ? 4 : 3;
    const int gbase = (wv < 4) ? 4*wv : 16 + 3*(wv - 4);

    // epilogue ownership (valid on quads 0-1): b = 2q + (n16>>3)
    const int b_lane = (2*q + (n16 >> 3)) & 3;

    // ---- stationary B fragments, biases, epilogue offsets per group ----
    half8 Bf[NGMAX][NTAU];
    float bias[NGMAX];
    int   eoff[NGMAX];      // fp16 offset within one [NTAU][32][8] buffer
    int   jcol[NGMAX];
    if (is_cw) {
        #pragma unroll
        for (int g = 0; g < NGMAX; ++g) {
            const int jbase = (gbase + g) * 8;
            const int j = jbase + jl;
            jcol[g] = j;
            const bool act = (g < ng) && (j < HID);
            bias[g] = act ? bvec[j] : 0.0f;
            // h(b_lane, j): tau=j>>6, slot=((j>>3)&3)*8 + b_lane*2 + ((j>>5)&1)
            eoff[g] = (j >> 6)*256
                    + ((((j >> 3) & 3)*8) + b_lane*2 + ((j >> 5) & 1))*8
                    + (j & 7);
            #pragma unroll
            for (int tau = 0; tau < NTAU; ++tau) {
                half8 f;
                #pragma unroll
                for (int i = 0; i < 8; ++i) {
                    const int k = tau*64 + (n16 >> 3)*32 + q*8 + i;
                    float v = 0.0f;
                    if (act) {
                        if (k < HID)                          v = H[j*HID + k];
                        else if (k >= 224 && k < 224+IN_DIM)  v = U[(k-224)*HID + j];
                    }
                    f[i] = (_Float16)v;
                }
                Bf[g][tau] = f;
            }
        }
    }

    // ---- x stager (wave 7, lanes 0-15): depth-2 register pipeline ----
    // lane = b*4 + kq; x[xi] at k=224+xi -> tau3, slot = kq*8 + b*2 + 1.
    const int sb  = (lane >> 2) & 3;
    const int skq = lane & 3;
    const int sslot = skq*8 + sb*2 + 1;
    const float* xrow_s = x + (size_t)(b0 + sb) * IN_DIM + skq*8;
    const size_t tstride = (size_t)BATCH * IN_DIM;
    floatx4 sA0 = zero4, sA1 = zero4, sB0 = zero4, sB1 = zero4;

    auto issueLd = [&](int tn, floatx4& f0, floatx4& f1) {
        const float* p = xrow_s + (size_t)tn * tstride;
        f0 = *(const floatx4*)p;
        f1 = (skq < 3) ? *(const floatx4*)(p + 4) : zero4;  // IN=28 tail zeroed
    };
    auto commitX = [&](floatx4 f0, floatx4 f1, int buf) {
        half8 ax;
        ax[0] = (_Float16)f0[0]; ax[1] = (_Float16)f0[1];
        ax[2] = (_Float16)f0[2]; ax[3] = (_Float16)f0[3];
        ax[4] = (_Float16)f1[0]; ax[5] = (_Float16)f1[1];
        ax[6] = (_Float16)f1[2]; ax[7] = (_Float16)f1[3];
        *(half8*)&lds_A[buf][3][sslot][0] = ax;
    };

    __syncthreads();   // zero-fill visible before prologue writes

    if (wv == 7 && lane < 16) {
        floatx4 t0, t1;
        issueLd(0, t0, t1);           // x[0]
        issueLd(1, sA0, sA1);         // x[1] -> slot A
        issueLd(2, sB0, sB1);         // x[2] -> slot B
        commitX(t0, t1, 0);           // x[0] into buf 0 (read at step 0)
    }

    auto computeStep = [&](int rb, int wb, bool last) {
        if (!is_cw) return;
        half8 av[NTAU];
        #pragma unroll
        for (int tau = 0; tau < NTAU; ++tau)
            av[tau] = *(const half8*)&lds_A[rb][tau][aslot][0];
        _Float16* wbase = &lds_A[wb][0][0][0];
        #pragma unroll
        for (int g = 0; g < NGMAX; ++g) {
            if (g < ng) {                      // wave-uniform
                floatx4 a = {bias[g], 0.0f, 0.0f, bias[g]};
                #pragma unroll
                for (int tau = 0; tau < NTAU; ++tau)
                    a = mfma16(av[tau], Bf[g][tau], a);
                // lane keeps r0 (lo) / r3 (hi); partner supplies r1/r2.
                const float send = (n16 < 8) ? a[2] : a[1];
                const float recv = ror8(send);           // full-EXEC
                const float s = ((n16 < 8) ? a[0] : a[3]) + recv;
                const float v = fast_tanh(s);
                if (q < 2 && jcol[g] < HID) {            // quads 2-3 are dups
                    wbase[eoff[g]] = (_Float16)v;
                    if (last) lds_h[b_lane][jcol[g]] = v;
                }
            }
        }
    };

    // ================= time loop, 2 steps/iter (static reg slots) =========
    // even step t:  commit slot A (x[t+1]) -> buf1, refill A with x[t+3]
    // odd step t+1: commit slot B (x[t+2]) -> buf0, refill B with x[t+4]
    #pragma unroll 1
    for (int t = 0; t < T_STEPS; t += 2) {
        __syncthreads();
        if (wv == 7 && lane < 16) {
            commitX(sA0, sA1, 1);
            const int tn = (t+3 < T_STEPS) ? (t+3) : (T_STEPS-1);
            issueLd(tn, sA0, sA1);
        }
        computeStep(0, 1, false);

        __syncthreads();
        if (wv == 7 && lane < 16) {
            commitX(sB0, sB1, 0);
            const int tn = (t+4 < T_STEPS) ? (t+4) : (T_STEPS-1);
            issueLd(tn, sB0, sB1);
        }
        computeStep(1, 0, (t + 2) == T_STEPS);
    }

    __syncthreads();

    // ---- output: out[b][o] = sum_k h[b][k]*A[o][k] + c[o] (tiny, scalar) ----
    if (tid < BB * OUT_DIM) {
        const int r = tid / OUT_DIM;
        const int o = tid % OUT_DIM;
        float s = cvec[o];
        for (int k = 0; k < HID; ++k) s += lds_h[r][k] * A[o*HID + k];
        out[(size_t)(b0 + r) * OUT_DIM + o] = s;
    }
}

extern "C" void kernel_launch(void* const* d_in, const int* in_sizes, int n_in,
                              void* d_out, int out_size, void* d_ws, size_t ws_size,
                              hipStream_t stream) {
    const float* x  = (const float*)d_in[0];
    const float* H  = (const float*)d_in[1];
    const float* U  = (const float*)d_in[2];
    const float* A  = (const float*)d_in[3];
    const float* b  = (const float*)d_in[4];
    const float* c  = (const float*)d_in[5];
    float* out = (float*)d_out;

    rnn_kernel<<<dim3(BATCH / BB), dim3(NTHREADS), 0, stream>>>(x, H, U, A, b, c, out);
}

// Round 7
// 456.017 us; speedup vs baseline: 1.4352x; 1.4352x over previous
//
#include <hip/hip_runtime.h>

// SimpleRNN: h_{t+1} = tanh(h_t @ H^T + x_t @ U + b); out = h_T @ A^T + c
// T=512 B=2048 IN=28 HID=198 OUT=10, fp32 in/out, fp16 recurrence.
//
// R15 = R12 with the per-step __syncthreads replaced by producer/consumer
// FLAG SYNC in LDS. Evidence trail: R12 killed bank conflicts with zero
// time change; pipe sums (LDS ~694 + matrix ~620 + VALU ~500) ~= 1810 vs
// step 1434 -> phases run ~80% serial because the barrier resets wave skew
// every step. R13/R14 closed the 2-blocks/CU route (BB=4 => 25% MFMA
// efficiency cap + no co-residency). So: desync the 16 waves of ONE block.
//
// Flag protocol (all in LDS, one block):
//   A-slot k-ranges align with producing waves: tau T (k in [64T,64T+64))
//   is written by waves 4T..4T+3 (j == k), tau3 by wave 12 + stager.
//   PROD[buf][tau]: completions (wave-units). RD[buf]: consumer completions.
//   Consumer step t (rb=t&1): spin PROD[rb][tau] >= nprod[tau]*np_rb
//     (nprod = {4,4,4,2}), read frags, MFMA, then signal RD[rb] (lane 0).
//   Producer: after tanh, spin RD[wb] >= 13*nr_wb, write frags, signal
//     PROD[wb][wv>>2]. Stager same for its x commit (PROD[wb][3]).
//   np/nr are per-wave round counters (monotone -> no reset races).
//   Signals: __hip_atomic_fetch_add RELEASE (orders prior ds_writes, and
//   the DS pipe is in-order per wave); spins: acquire loads, all lanes on
//   the same address (broadcast, cheap); ds_add gated to lane 0 (per-lane
//   semantics!). No __syncthreads in the loop -> waves skew freely, LDS
//   burst of one wave overlaps MFMA/tanh of others; stager global loads
//   are never drained at a barrier (truly async now).
//
// Structure otherwise R12 (passed, absmax 0.0078): diagonal-block MFMA,
// BB=8, 16 waves, lane l reads A-slot l (linear, conflict-free), combine
// via full-EXEC row_ror:8 (R10 lesson), depth-2 stager pipeline.

#define T_STEPS 512
#define BATCH   2048
#define IN_DIM  28
#define HID     198
#define OUT_DIM 10
#define BB      8      // batch rows per block
#define NTAU    4      // K-tiles of 64: 4*64=256 >= 198+28(+pad)
#define NTHREADS 1024  // 16 waves
#define NCW     13     // consumer/producer compute waves

typedef __attribute__((ext_vector_type(8))) _Float16 half8;
typedef __attribute__((ext_vector_type(4))) float   floatx4;

__device__ __forceinline__ floatx4 mfma16(half8 a, half8 b, floatx4 c) {
    return __builtin_amdgcn_mfma_f32_16x16x32_f16(a, b, c, 0, 0, 0);
}

// tanh(x) = 1 - 2/(exp(2x)+1); exp2-based, saturates via IEEE inf/0.
__device__ __forceinline__ float fast_tanh(float x) {
    float e = __builtin_amdgcn_exp2f(x * 2.885390081777926357f); // exp(2x)
    float r = __builtin_amdgcn_rcpf(e + 1.0f);
    return __builtin_fmaf(-2.0f, r, 1.0f);
}

// lane <- lane^8 within each 16-lane DPP row. Full-EXEC straight-line only.
__device__ __forceinline__ float ror8(float v) {
    return __builtin_bit_cast(float,
        __builtin_amdgcn_mov_dpp(__builtin_bit_cast(int, v),
                                 0x128 /*row_ror:8*/, 0xf, 0xf, true));
}

__device__ __forceinline__ void spin_ge(unsigned* f, unsigned target) {
    while (__hip_atomic_load(f, __ATOMIC_ACQUIRE,
                             __HIP_MEMORY_SCOPE_WORKGROUP) < target) { }
}
__device__ __forceinline__ void signal_add(unsigned* f) {
    __hip_atomic_fetch_add(f, 1u, __ATOMIC_RELEASE,
                           __HIP_MEMORY_SCOPE_WORKGROUP);
}

__global__ void __launch_bounds__(NTHREADS, 4)
rnn_kernel(const float* __restrict__ x, const float* __restrict__ H,
           const float* __restrict__ U, const float* __restrict__ A,
           const float* __restrict__ bvec, const float* __restrict__ cvec,
           float* __restrict__ out)
{
    // [buf][tau][slot][idx] fp16; slot(b,khalf,kq) = kq*16+(b>>1)*4+(b&1)*2+khalf
    // (inverse of lane map: compute lane l reads b128 at slot l, conflict-free).
    __shared__ __align__(16) _Float16 lds_A[2][NTAU][64][8];   // 8 KB
    __shared__ float lds_h[BB][204];                            // final h, fp32
    // flags: prod[buf][tau] = s_flags[buf*4+tau]; rd[buf] = s_flags[8+buf]
    __shared__ unsigned s_flags[10];

    const int tid  = threadIdx.x;
    const int lane = tid & 63;
    const int wv   = tid >> 6;          // wave id 0..15
    const int n16  = lane & 15;         // MFMA row(A)/col(B,C) index
    const int q    = lane >> 4;         // 0..3 (k-octet within 32-subtile)
    const int b0   = blockIdx.x * BB;

    // zero-init both buffers (h0 = 0; phantom K slots stay 0 forever)
    {
        _Float16* p0 = &lds_A[0][0][0][0];
        for (int i = tid; i < 2*NTAU*64*8; i += NTHREADS) p0[i] = (_Float16)0.0f;
    }
    if (tid == 0) {
        // round-0 of buf0 "produced" by the zero-init (h0 = 0), EXCEPT the
        // stager's x[0] share of tau3: init 1 of 2, stager adds the other.
        s_flags[0] = 4; s_flags[1] = 4; s_flags[2] = 4; s_flags[3] = 1;
        s_flags[4] = 0; s_flags[5] = 0; s_flags[6] = 0; s_flags[7] = 0;
        s_flags[8] = 0; s_flags[9] = 0;
    }

    const floatx4 zero4 = {0.0f, 0.0f, 0.0f, 0.0f};
    const bool is_cw = (wv < NCW);

    const int aslot = lane;             // linear A-read (R12)

    // ---- col groups: g0 = cols wv*16..+7, g1 = wv*16+8..+15 ----
    const int jbase0 = wv*16;
    const int jbase1 = wv*16 + 8;
    const bool g1_on = is_cw && (jbase1 < HID);     // wave 12: g1 all-phantom
    const int jl = n16 & 7;
    const int j0 = jbase0 + jl;
    const int j1 = jbase1 + jl;
    // epilogue ownership: lane (n16,q) finishes batch row 2q + (n16>>3)
    const int b_lane = 2*q + (n16 >> 3);

    // ---- stationary fp16 B fragments (H + U), diagonal k-half layout ----
    half8 Bf0[NTAU], Bf1[NTAU];
    float bias0 = 0.0f, bias1 = 0.0f;
    if (is_cw) {
        bias0 = (n16 < 8 && j0 < HID) ? bvec[j0] : 0.0f;   // bias on lo-cols only
        bias1 = (n16 < 8 && g1_on)    ? bvec[j1] : 0.0f;
        #pragma unroll
        for (int tau = 0; tau < NTAU; ++tau) {
            half8 f0, f1;
            #pragma unroll
            for (int i = 0; i < 8; ++i) {
                const int k = tau*64 + (n16 >> 3)*32 + q*8 + i;
                float v0 = 0.0f, v1 = 0.0f;
                if (j0 < HID) {
                    if (k < HID)                          v0 = H[j0*HID + k];
                    else if (k >= 224 && k < 224+IN_DIM)  v0 = U[(k-224)*HID + j0];
                }
                if (g1_on) {
                    if (k < HID)                          v1 = H[j1*HID + k];
                    else if (k >= 224 && k < 224+IN_DIM)  v1 = U[(k-224)*HID + j1];
                }
                f0[i] = (_Float16)v0;
                f1[i] = (_Float16)v1;
            }
            Bf0[tau] = f0; Bf1[tau] = f1;
        }
    }

    // epilogue write addresses for h(b_lane, j)
    const int e0_tau  = j0 >> 6;
    const int e0_slot = ((j0 >> 3) & 3)*16 + (b_lane >> 1)*4 + (b_lane & 1)*2
                      + ((j0 >> 5) & 1);
    const int e0_idx  = j0 & 7;
    const int e1_tau  = j1 >> 6;
    const int e1_slot = ((j1 >> 3) & 3)*16 + (b_lane >> 1)*4 + (b_lane & 1)*2
                      + ((j1 >> 5) & 1);
    const int e1_idx  = j1 & 7;

    // ---- x stager (wave 15, lanes 0-31): depth-2 register pipeline ----
    const int srow = lane & 31, sq = srow >> 3, sr8 = srow & 7;
    const int sslot = sq*16 + (sr8 >> 1)*4 + (sr8 & 1)*2 + 1;
    const float* xrow_s = x + (size_t)(b0 + sr8) * IN_DIM + sq*8;
    const size_t tstride = (size_t)BATCH * IN_DIM;
    floatx4 sA0 = zero4, sA1 = zero4, sB0 = zero4, sB1 = zero4;

    auto issueLd = [&](int tn, floatx4& f0, floatx4& f1) {
        const float* p = xrow_s + (size_t)tn * tstride;
        f0 = *(const floatx4*)p;
        f1 = (sq < 3) ? *(const floatx4*)(p + 4) : zero4;   // IN=28 tail zeroed
    };
    auto commitX = [&](floatx4 f0, floatx4 f1, int buf) {
        half8 ax;
        ax[0] = (_Float16)f0[0]; ax[1] = (_Float16)f0[1];
        ax[2] = (_Float16)f0[2]; ax[3] = (_Float16)f0[3];
        ax[4] = (_Float16)f1[0]; ax[5] = (_Float16)f1[1];
        ax[6] = (_Float16)f1[2]; ax[7] = (_Float16)f1[3];
        *(half8*)&lds_A[buf][3][sslot][0] = ax;
    };

    __syncthreads();   // zero-fill + flag init visible

    if (wv == 15) {
        if (lane < 32) {
            floatx4 t0, t1;
            issueLd(0, t0, t1);           // x[0]
            issueLd(1, sA0, sA1);         // x[1] -> slot A
            issueLd(2, sB0, sB1);         // x[2] -> slot B
            commitX(t0, t1, 0);           // x[0] into buf 0 (read at step 0)
        }
        if (lane == 0) signal_add(&s_flags[3]);   // PROD[0][3]: 1 -> 2
    }

    auto computeStep = [&](int rb, int wb, bool last, unsigned np, unsigned nrw) {
        if (!is_cw) return;
        // producers of the read buffer done?
        spin_ge(&s_flags[rb*4+0], 4u*np);
        spin_ge(&s_flags[rb*4+1], 4u*np);
        spin_ge(&s_flags[rb*4+2], 4u*np);
        spin_ge(&s_flags[rb*4+3], 2u*np);
        half8 av[NTAU];
        #pragma unroll
        for (int tau = 0; tau < NTAU; ++tau)
            av[tau] = *(const half8*)&lds_A[rb][tau][aslot][0];
        floatx4 a0 = {bias0, bias0, bias0, bias0};
        floatx4 a1 = {bias1, bias1, bias1, bias1};
        #pragma unroll
        for (int tau = 0; tau < NTAU; ++tau) {
            a0 = mfma16(av[tau], Bf0[tau], a0);
            if (g1_on) a1 = mfma16(av[tau], Bf1[tau], a1);
        }
        if (lane == 0) signal_add(&s_flags[8+rb]);   // reads consumed
        // combine diagonal partials (full-EXEC DPP), then tanh
        const float send0 = (n16 < 8) ? a0[2] : a0[1];
        const float send1 = (n16 < 8) ? a1[2] : a1[1];
        const float recv0 = ror8(send0);
        const float recv1 = ror8(send1);
        const float s0 = ((n16 < 8) ? a0[0] : a0[3]) + recv0;
        const float s1 = ((n16 < 8) ? a1[0] : a1[3]) + recv1;
        const float v0 = fast_tanh(s0);
        const float v1 = fast_tanh(s1);
        spin_ge(&s_flags[8+wb], 13u*nrw);            // write buffer drained?
        if (j0 < HID) {
            lds_A[wb][e0_tau][e0_slot][e0_idx] = (_Float16)v0;
            if (last) lds_h[b_lane][j0] = v0;
        }
        if (g1_on) {
            lds_A[wb][e1_tau][e1_slot][e1_idx] = (_Float16)v1;
            if (last) lds_h[b_lane][j1] = v1;
        }
        if (lane == 0) signal_add(&s_flags[wb*4 + (wv >> 2)]);
    };

    // ===== time loop, 2 steps/iter; NO barriers, flag-sync only =====
    unsigned np0 = 1, np1 = 1;   // consumer round targets per buffer
    unsigned nr0 = 1, nr1 = 0;   // producer round targets per buffer
    #pragma unroll 1
    for (int t = 0; t < T_STEPS; t += 2) {
        // ---- even step: rb=0, wb=1 ----
        if (wv == 15) {
            if (lane < 32) {
                spin_ge(&s_flags[9], 13u*nr1);
                commitX(sA0, sA1, 1);
            }
            if (lane == 0) signal_add(&s_flags[4+3]);
            if (lane < 32) {
                const int tn = (t+3 < T_STEPS) ? (t+3) : (T_STEPS-1);
                issueLd(tn, sA0, sA1);
            }
        }
        computeStep(0, 1, false, np0, nr1);
        np0 += 1; nr1 += 1;

        // ---- odd step: rb=1, wb=0 ----
        if (wv == 15) {
            if (lane < 32) {
                spin_ge(&s_flags[8], 13u*nr0);
                commitX(sB0, sB1, 0);
            }
            if (lane == 0) signal_add(&s_flags[0+3]);
            if (lane < 32) {
                const int tn = (t+4 < T_STEPS) ? (t+4) : (T_STEPS-1);
                issueLd(tn, sB0, sB1);
            }
        }
        computeStep(1, 0, (t + 2) == T_STEPS, np1, nr0);
        np1 += 1; nr0 += 1;
    }

    __syncthreads();   // lds_h published

    // ---- output: out[b][o] = sum_k h[b][k]*A[o][k] + c[o] (tiny, scalar) ----
    if (tid < BB * OUT_DIM) {
        const int r = tid / OUT_DIM;
        const int o = tid % OUT_DIM;
        float s = cvec[o];
        for (int k = 0; k < HID; ++k) s += lds_h[r][k] * A[o*HID + k];
        out[(size_t)(b0 + r) * OUT_DIM + o] = s;
    }
}

extern "C" void kernel_launch(void* const* d_in, const int* in_sizes, int n_in,
                              void* d_out, int out_size, void* d_ws, size_t ws_size,
                              hipStream_t stream) {
    const float* x  = (const float*)d_in[0];
    const float* H  = (const float*)d_in[1];
    const float* U  = (const float*)d_in[2];
    const float* A  = (const float*)d_in[3];
    const float* b  = (const float*)d_in[4];
    const float* c  = (const float*)d_in[5];
    float* out = (float*)d_out;

    rnn_kernel<<<dim3(BATCH / BB), dim3(NTHREADS), 0, stream>>>(x, H, U, A, b, c, out);
}

// Round 8
// 415.335 us; speedup vs baseline: 1.5758x; 1.0979x over previous
//
#include <hip/hip_runtime.h>

// SimpleRNN: h_{t+1} = tanh(h_t @ H^T + x_t @ U + b); out = h_T @ A^T + c
// T=512 B=2048 IN=28 HID=198 OUT=10, fp32 in/out, fp16 recurrence.
//
// R16: heavy-wave diagonal — 8 waves, 7 compute waves x ~4 j-octets.
// Ledger: R12 (306us, step 1434) = LDS burst ~600 (52 b128: 13 waves all
// re-read the same 4KB h) + VALU ~500 (invariant) + MFMA ~200 + barrier.
// R15 (flag sync) closed the sync-replacement branch: LDS-atomic spins
// cost ~280cyc/step MORE than s_barrier. Remaining lever: LDS reads scale
// with #compute-waves (diagonal layout: 4 b128/wave regardless of octet
// count). 7 compute waves => 28 reads (-300cyc pipe). R9's fewer-wave
// failure was confounded (duplicated-row layout, 8 reads/wave, 2 chains);
// here per-wave ILP is 4 independent MFMA chains.
// Octet balance (stager on wave 3, SIMD = wv%4): waves 0,1,2,7 -> 4
// octets, waves 4,5,6 -> 3 octets (25 total); per-SIMD octets {7,7,7,4}.
// VGPR ~150 (Bf[4][4]=64): __launch_bounds__(512,1) keeps cap >=256 under
// either launch_bounds semantics (R13/R14 lesson).
//
// Proven components kept verbatim from R12 (passed, absmax 0.0078):
// - diagonal k-half MFMA: A row m=4q+r carries (b=2q+(r>>1), khalf=r&1);
//   B cols 0-7 = j-octet @ k-lo, 8-15 same @ k-hi; per MFMA: 8 cols x K=64.
// - lane l reads A-slot l (linear b128, conflict-free; R12: 27.3M->538K);
//   writers use inverse map slot(b,kh,kq) = kq*16+(b>>1)*4+(b&1)*2+kh.
// - combine: pre-select partner value, ONE full-EXEC row_ror:8, select+add
//   (R10 lesson: no convergent op under lane-divergent control).
// - bias on lo-lanes in all 4 acc regs -> lands exactly once after combine.
// - K layout: k 0..197 = H, 224..251 = x (tau3 khi), gaps zero forever.
// - depth-2 stager reg pipeline (wave 3): load x[t+3] during t, commit t+2.
// - one s_barrier per step (hardware barrier beats any LDS handshake).

#define T_STEPS 512
#define BATCH   2048
#define IN_DIM  28
#define HID     198
#define OUT_DIM 10
#define BB      8      // batch rows per block
#define NTAU    4      // K-tiles of 64: 4*64=256 >= 198+28(+pad)
#define NTHREADS 512   // 8 waves
#define NGMAX   4      // max j-octet groups per wave

typedef __attribute__((ext_vector_type(8))) _Float16 half8;
typedef __attribute__((ext_vector_type(4))) float   floatx4;

__device__ __forceinline__ floatx4 mfma16(half8 a, half8 b, floatx4 c) {
    return __builtin_amdgcn_mfma_f32_16x16x32_f16(a, b, c, 0, 0, 0);
}

// tanh(x) = 1 - 2/(exp(2x)+1); exp2-based, saturates via IEEE inf/0.
__device__ __forceinline__ float fast_tanh(float x) {
    float e = __builtin_amdgcn_exp2f(x * 2.885390081777926357f); // exp(2x)
    float r = __builtin_amdgcn_rcpf(e + 1.0f);
    return __builtin_fmaf(-2.0f, r, 1.0f);
}

// lane <- lane^8 within each 16-lane DPP row. Full-EXEC straight-line only.
__device__ __forceinline__ float ror8(float v) {
    return __builtin_bit_cast(float,
        __builtin_amdgcn_mov_dpp(__builtin_bit_cast(int, v),
                                 0x128 /*row_ror:8*/, 0xf, 0xf, true));
}

__global__ void __launch_bounds__(NTHREADS, 1)
rnn_kernel(const float* __restrict__ x, const float* __restrict__ H,
           const float* __restrict__ U, const float* __restrict__ A,
           const float* __restrict__ bvec, const float* __restrict__ cvec,
           float* __restrict__ out)
{
    // [buf][tau][slot][idx] fp16; compute lane l reads b128 at slot l.
    __shared__ __align__(16) _Float16 lds_A[2][NTAU][64][8];   // 8 KB
    __shared__ float lds_h[BB][204];                            // final h, fp32

    const int tid  = threadIdx.x;
    const int lane = tid & 63;
    const int wv   = tid >> 6;          // wave id 0..7
    const int n16  = lane & 15;         // MFMA row(A)/col(B,C) index
    const int q    = lane >> 4;         // 0..3 (k-octet within 32-subtile)
    const int jl   = n16 & 7;
    const int b0   = blockIdx.x * BB;

    // zero-init both buffers (h0 = 0; phantom K slots stay 0 forever)
    {
        _Float16* p0 = &lds_A[0][0][0][0];
        for (int i = tid; i < 2*NTAU*64*8; i += NTHREADS) p0[i] = (_Float16)0.0f;
    }

    const floatx4 zero4 = {0.0f, 0.0f, 0.0f, 0.0f};
    const bool is_cw = (wv != 3);       // wave 3 = stager

    // octet groups: waves 0,1,2 -> {4w..4w+3}; wave 7 -> {21..24};
    // waves 4,5,6 -> {12+3(w-4) ..+2}. 25 octets total (octet 24: j>=192,
    // jl 6,7 phantom). Per-SIMD octet load {7,7,7,4}.
    const int ng    = (wv == 3) ? 0 : ((wv < 3 || wv == 7) ? 4 : 3);
    const int gbase = (wv < 3) ? 4*wv : ((wv == 7) ? 21 : 12 + 3*(wv - 4));

    // epilogue ownership: lane (n16,q) finishes batch row 2q + (n16>>3)
    const int b_lane = 2*q + (n16 >> 3);

    // ---- stationary B fragments, biases, epilogue offsets per group ----
    half8 Bf[NGMAX][NTAU];
    float bias[NGMAX];
    int   eoff[NGMAX];      // fp16 offset within one [NTAU][64][8] buffer
    int   jcol[NGMAX];
    if (is_cw) {
        #pragma unroll
        for (int g = 0; g < NGMAX; ++g) {
            const int j = (gbase + g)*8 + jl;
            jcol[g] = j;
            const bool act = (g < ng) && (j < HID);
            bias[g] = (act && n16 < 8) ? bvec[j] : 0.0f;   // lo-lanes only
            const int eslot = ((j >> 3) & 3)*16 + (b_lane >> 1)*4
                            + (b_lane & 1)*2 + ((j >> 5) & 1);
            eoff[g] = (j >> 6)*512 + eslot*8 + (j & 7);
            #pragma unroll
            for (int tau = 0; tau < NTAU; ++tau) {
                half8 f;
                #pragma unroll
                for (int i = 0; i < 8; ++i) {
                    const int k = tau*64 + (n16 >> 3)*32 + q*8 + i;
                    float v = 0.0f;
                    if (act) {
                        if (k < HID)                          v = H[j*HID + k];
                        else if (k >= 224 && k < 224+IN_DIM)  v = U[(k-224)*HID + j];
                    }
                    f[i] = (_Float16)v;
                }
                Bf[g][tau] = f;
            }
        }
    }

    // ---- x stager (wave 3, lanes 0-31): depth-2 register pipeline ----
    const int srow = lane & 31, sq = srow >> 3, sr8 = srow & 7;
    const int sslot = sq*16 + (sr8 >> 1)*4 + (sr8 & 1)*2 + 1;
    const float* xrow_s = x + (size_t)(b0 + sr8) * IN_DIM + sq*8;
    const size_t tstride = (size_t)BATCH * IN_DIM;
    floatx4 sA0 = zero4, sA1 = zero4, sB0 = zero4, sB1 = zero4;

    auto issueLd = [&](int tn, floatx4& f0, floatx4& f1) {
        const float* p = xrow_s + (size_t)tn * tstride;
        f0 = *(const floatx4*)p;
        f1 = (sq < 3) ? *(const floatx4*)(p + 4) : zero4;   // IN=28 tail zeroed
    };
    auto commitX = [&](floatx4 f0, floatx4 f1, int buf) {
        half8 ax;
        ax[0] = (_Float16)f0[0]; ax[1] = (_Float16)f0[1];
        ax[2] = (_Float16)f0[2]; ax[3] = (_Float16)f0[3];
        ax[4] = (_Float16)f1[0]; ax[5] = (_Float16)f1[1];
        ax[6] = (_Float16)f1[2]; ax[7] = (_Float16)f1[3];
        *(half8*)&lds_A[buf][3][sslot][0] = ax;
    };

    __syncthreads();   // zero-fill visible before prologue writes

    if (wv == 3 && lane < 32) {
        floatx4 t0, t1;
        issueLd(0, t0, t1);           // x[0]
        issueLd(1, sA0, sA1);         // x[1] -> slot A
        issueLd(2, sB0, sB1);         // x[2] -> slot B
        commitX(t0, t1, 0);           // x[0] into buf 0 (read at step 0)
    }

    auto computeStep = [&](int rb, int wb, bool last) {
        if (!is_cw) return;
        half8 av[NTAU];
        #pragma unroll
        for (int tau = 0; tau < NTAU; ++tau)
            av[tau] = *(const half8*)&lds_A[rb][tau][lane][0];
        floatx4 acc[NGMAX];
        #pragma unroll
        for (int g = 0; g < NGMAX; ++g)
            acc[g] = (floatx4){bias[g], bias[g], bias[g], bias[g]};
        // tau-outer, group-inner: up to 4 independent MFMA chains (ILP)
        #pragma unroll
        for (int tau = 0; tau < NTAU; ++tau) {
            #pragma unroll
            for (int g = 0; g < NGMAX; ++g)
                if (g < ng) acc[g] = mfma16(av[tau], Bf[g][tau], acc[g]);
        }
        _Float16* wbase = &lds_A[wb][0][0][0];
        #pragma unroll
        for (int g = 0; g < NGMAX; ++g) {
            if (g < ng) {   // wave-uniform branch: full EXEC inside
                const floatx4 a = acc[g];
                // lane keeps r0 (b=2q,lo) / r3 (b=2q+1,hi); partner ^8
                // supplies r1/r2. Pre-select, ONE full-EXEC DPP, select+add.
                const float send = (n16 < 8) ? a[2] : a[1];
                const float recv = ror8(send);
                const float s = ((n16 < 8) ? a[0] : a[3]) + recv;
                const float v = fast_tanh(s);
                if (jcol[g] < HID) {            // lane-divergent: writes only
                    wbase[eoff[g]] = (_Float16)v;
                    if (last) lds_h[b_lane][jcol[g]] = v;
                }
            }
        }
    };

    // ================= time loop, 2 steps/iter (static reg slots) =========
    // even step t:  commit slot A (x[t+1]) -> buf1, refill A with x[t+3]
    // odd step t+1: commit slot B (x[t+2]) -> buf0, refill B with x[t+4]
    #pragma unroll 1
    for (int t = 0; t < T_STEPS; t += 2) {
        __syncthreads();
        if (wv == 3 && lane < 32) {
            commitX(sA0, sA1, 1);
            const int tn = (t+3 < T_STEPS) ? (t+3) : (T_STEPS-1);
            issueLd(tn, sA0, sA1);
        }
        computeStep(0, 1, false);

        __syncthreads();
        if (wv == 3 && lane < 32) {
            commitX(sB0, sB1, 0);
            const int tn = (t+4 < T_STEPS) ? (t+4) : (T_STEPS-1);
            issueLd(tn, sB0, sB1);
        }
        computeStep(1, 0, (t + 2) == T_STEPS);
    }

    __syncthreads();

    // ---- output: out[b][o] = sum_k h[b][k]*A[o][k] + c[o] (tiny, scalar) ----
    if (tid < BB * OUT_DIM) {
        const int r = tid / OUT_DIM;
        const int o = tid % OUT_DIM;
        float s = cvec[o];
        for (int k = 0; k < HID; ++k) s += lds_h[r][k] * A[o*HID + k];
        out[(size_t)(b0 + r) * OUT_DIM + o] = s;
    }
}

extern "C" void kernel_launch(void* const* d_in, const int* in_sizes, int n_in,
                              void* d_out, int out_size, void* d_ws, size_t ws_size,
                              hipStream_t stream) {
    const float* x  = (const float*)d_in[0];
    const float* H  = (const float*)d_in[1];
    const float* U  = (const float*)d_in[2];
    const float* A  = (const float*)d_in[3];
    const float* b  = (const float*)d_in[4];
    const float* c  = (const float*)d_in[5];
    float* out = (float*)d_out;

    rnn_kernel<<<dim3(BATCH / BB), dim3(NTHREADS), 0, stream>>>(x, H, U, A, b, c, out);
}

// Round 9
// 402.814 us; speedup vs baseline: 1.6248x; 1.0311x over previous
//
#include <hip/hip_runtime.h>

// SimpleRNN: h_{t+1} = tanh(h_t @ H^T + x_t @ U + b); out = h_T @ A^T + c
// T=512 B=2048 IN=28 HID=198 OUT=10, fp32 in/out, fp16 recurrence.
//
// R17 = R12 with the in-loop __syncthreads replaced by lgkmcnt-only
// barriers (s_waitcnt lgkmcnt(0) + raw s_barrier, AITER pattern).
//
// WHY: __syncthreads drains vmcnt(0) too. Wave 15's step is
// commitX -> issueLd(x[t+3]) -> barrier: the loads it just issued are
// force-drained ~20cy later, so the "depth-2 register pipeline" never
// spanned a barrier and the cold-HBM x latency (~900cy; every step's
// 229KB x-slice is first-touch across all 256 blocks) sat inside every
// barrier interval, gating all 16 waves. This explains the whole R12-R16
// ledger: step 1434 >> pipe sums ~1000; bank-conflict fix (R12) neutral;
// fewer-wave (R16) and flag-sync (R15) both regressions; MfmaUtil/VALUBusy
// stuck at ~32/36%. The lgkmcnt-only barrier drains LDS (h-visibility:
// producers' ds_writes complete before s_barrier) but leaves wave 15's
// global loads in flight; their consumer (commitX, 2 steps ~ 2800cy later)
// gets a compiler-inserted counted vmcnt wait that retires free.
// Fence discipline: asm-memory clobber before AND after s_barrier so no
// LDS op migrates across (compiler could otherwise hoist next step's
// ds_read above the barrier).
//
// Everything else identical to R12 (passed, 306us, absmax 0.0078):
// - diagonal k-half MFMA: A row m=4q+r carries (b=2q+(r>>1), khalf=r&1);
//   B cols 0-7 = j-octet @ k-lo, 8-15 same @ k-hi; per MFMA 8 cols x K=64.
// - lane l reads A-slot l (linear b128, conflict-free; 27.3M->538K);
//   writers use inverse map slot(b,kh,kq)=kq*16+(b>>1)*4+(b&1)*2+kh.
// - combine: pre-select partner value, ONE full-EXEC row_ror:8, select+add
//   (R10 lesson: no convergent op under lane-divergent control).
// - 16 waves / 13 compute (R9/R16: both 8-wave variants lose to 4/SIMD).
// - K layout: k 0..197 = H, 224..251 = x (tau3 k-hi), gaps zero forever.
// - depth-2 stager reg pipeline on wave 15 (now actually effective).

#define T_STEPS 512
#define BATCH   2048
#define IN_DIM  28
#define HID     198
#define OUT_DIM 10
#define BB      8      // batch rows per block
#define NTAU    4      // K-tiles of 64: 4*64=256 >= 198+28(+pad)
#define NTHREADS 1024  // 16 waves

typedef __attribute__((ext_vector_type(8))) _Float16 half8;
typedef __attribute__((ext_vector_type(4))) float   floatx4;

__device__ __forceinline__ floatx4 mfma16(half8 a, half8 b, floatx4 c) {
    return __builtin_amdgcn_mfma_f32_16x16x32_f16(a, b, c, 0, 0, 0);
}

// tanh(x) = 1 - 2/(exp(2x)+1); exp2-based, saturates via IEEE inf/0.
__device__ __forceinline__ float fast_tanh(float x) {
    float e = __builtin_amdgcn_exp2f(x * 2.885390081777926357f); // exp(2x)
    float r = __builtin_amdgcn_rcpf(e + 1.0f);
    return __builtin_fmaf(-2.0f, r, 1.0f);
}

// lane <- lane^8 within each 16-lane DPP row. Full-EXEC straight-line only.
__device__ __forceinline__ float ror8(float v) {
    return __builtin_bit_cast(float,
        __builtin_amdgcn_mov_dpp(__builtin_bit_cast(int, v),
                                 0x128 /*row_ror:8*/, 0xf, 0xf, true));
}

// Workgroup barrier that drains LDS (lgkmcnt) but NOT global loads (vmcnt).
// Memory-clobber asm on both sides: no LDS op may migrate across.
__device__ __forceinline__ void lds_barrier() {
    asm volatile("s_waitcnt lgkmcnt(0)" ::: "memory");
    __builtin_amdgcn_s_barrier();
    asm volatile("" ::: "memory");
}

__global__ void __launch_bounds__(NTHREADS, 4)
rnn_kernel(const float* __restrict__ x, const float* __restrict__ H,
           const float* __restrict__ U, const float* __restrict__ A,
           const float* __restrict__ bvec, const float* __restrict__ cvec,
           float* __restrict__ out)
{
    // [buf][tau][slot][idx] fp16; slot(b,khalf,kq) = kq*16+(b>>1)*4+(b&1)*2+khalf
    // (inverse of lane map: compute lane l reads b128 at slot l, conflict-free).
    __shared__ __align__(16) _Float16 lds_A[2][NTAU][64][8];   // 8 KB
    __shared__ float lds_h[BB][204];                            // final h, fp32

    const int tid  = threadIdx.x;
    const int lane = tid & 63;
    const int wv   = tid >> 6;          // wave id 0..15
    const int n16  = lane & 15;         // MFMA row(A)/col(B,C) index
    const int q    = lane >> 4;         // 0..3 (k-octet within 32-subtile)
    const int b0   = blockIdx.x * BB;

    // zero-init both buffers (h0 = 0; phantom K slots stay 0 forever)
    {
        _Float16* p0 = &lds_A[0][0][0][0];
        for (int i = tid; i < 2*NTAU*64*8; i += NTHREADS) p0[i] = (_Float16)0.0f;
    }

    const floatx4 zero4 = {0.0f, 0.0f, 0.0f, 0.0f};
    const bool is_cw = (wv < 13);       // compute waves

    const int aslot = lane;             // linear A-read (R12)

    // ---- col groups: g0 = cols wv*16..+7, g1 = wv*16+8..+15 ----
    const int jbase0 = wv*16;
    const int jbase1 = wv*16 + 8;
    const bool g1_on = is_cw && (jbase1 < HID);     // wave 12: g1 all-phantom
    const int jl = n16 & 7;
    const int j0 = jbase0 + jl;
    const int j1 = jbase1 + jl;
    // epilogue ownership: lane (n16,q) finishes batch row 2q + (n16>>3)
    const int b_lane = 2*q + (n16 >> 3);

    // ---- stationary fp16 B fragments (H + U), diagonal k-half layout ----
    half8 Bf0[NTAU], Bf1[NTAU];
    float bias0 = 0.0f, bias1 = 0.0f;
    if (is_cw) {
        bias0 = (n16 < 8 && j0 < HID) ? bvec[j0] : 0.0f;   // bias on lo-cols only
        bias1 = (n16 < 8 && g1_on)    ? bvec[j1] : 0.0f;
        #pragma unroll
        for (int tau = 0; tau < NTAU; ++tau) {
            half8 f0, f1;
            #pragma unroll
            for (int i = 0; i < 8; ++i) {
                const int k = tau*64 + (n16 >> 3)*32 + q*8 + i;
                float v0 = 0.0f, v1 = 0.0f;
                if (j0 < HID) {
                    if (k < HID)                          v0 = H[j0*HID + k];
                    else if (k >= 224 && k < 224+IN_DIM)  v0 = U[(k-224)*HID + j0];
                }
                if (g1_on) {
                    if (k < HID)                          v1 = H[j1*HID + k];
                    else if (k >= 224 && k < 224+IN_DIM)  v1 = U[(k-224)*HID + j1];
                }
                f0[i] = (_Float16)v0;
                f1[i] = (_Float16)v1;
            }
            Bf0[tau] = f0; Bf1[tau] = f1;
        }
    }

    // epilogue write addresses for h(b_lane, j)
    const int e0_tau  = j0 >> 6;
    const int e0_slot = ((j0 >> 3) & 3)*16 + (b_lane >> 1)*4 + (b_lane & 1)*2
                      + ((j0 >> 5) & 1);
    const int e0_idx  = j0 & 7;
    const int e1_tau  = j1 >> 6;
    const int e1_slot = ((j1 >> 3) & 3)*16 + (b_lane >> 1)*4 + (b_lane & 1)*2
                      + ((j1 >> 5) & 1);
    const int e1_idx  = j1 & 7;

    // ---- x stager (wave 15, lanes 0-31): depth-2 register pipeline ----
    const int srow = lane & 31, sq = srow >> 3, sr8 = srow & 7;
    const int sslot = sq*16 + (sr8 >> 1)*4 + (sr8 & 1)*2 + 1;
    const float* xrow_s = x + (size_t)(b0 + sr8) * IN_DIM + sq*8;
    const size_t tstride = (size_t)BATCH * IN_DIM;
    floatx4 sA0 = zero4, sA1 = zero4, sB0 = zero4, sB1 = zero4;

    auto issueLd = [&](int tn, floatx4& f0, floatx4& f1) {
        const float* p = xrow_s + (size_t)tn * tstride;
        f0 = *(const floatx4*)p;
        f1 = (sq < 3) ? *(const floatx4*)(p + 4) : zero4;   // IN=28 tail zeroed
    };
    auto commitX = [&](floatx4 f0, floatx4 f1, int buf) {
        half8 ax;
        ax[0] = (_Float16)f0[0]; ax[1] = (_Float16)f0[1];
        ax[2] = (_Float16)f0[2]; ax[3] = (_Float16)f0[3];
        ax[4] = (_Float16)f1[0]; ax[5] = (_Float16)f1[1];
        ax[6] = (_Float16)f1[2]; ax[7] = (_Float16)f1[3];
        *(half8*)&lds_A[buf][3][sslot][0] = ax;
    };

    __syncthreads();   // zero-fill visible before prologue writes

    if (wv == 15 && lane < 32) {
        floatx4 t0, t1;
        issueLd(0, t0, t1);           // x[0]
        issueLd(1, sA0, sA1);         // x[1] -> slot A
        issueLd(2, sB0, sB1);         // x[2] -> slot B
        commitX(t0, t1, 0);           // x[0] into buf 0 (read at step 0)
    }

    auto computeStep = [&](int rb, int wb, bool last) {
        if (!is_cw) return;
        half8 av[NTAU];
        #pragma unroll
        for (int tau = 0; tau < NTAU; ++tau)
            av[tau] = *(const half8*)&lds_A[rb][tau][aslot][0];
        floatx4 a0 = {bias0, bias0, bias0, bias0};
        floatx4 a1 = {bias1, bias1, bias1, bias1};
        #pragma unroll
        for (int tau = 0; tau < NTAU; ++tau) {
            a0 = mfma16(av[tau], Bf0[tau], a0);
            if (g1_on) a1 = mfma16(av[tau], Bf1[tau], a1);
        }
        // ---- combine diagonal partials, DPP in full-EXEC straight line ----
        // Lane holds D[4q+r][n16]: r0=(b=2q,lo) r1=(b=2q,hi) r2=(b=2q+1,lo)
        // r3=(b=2q+1,hi). Lo-lane (n16<8) finishes b=2q, needs partner's r1;
        // hi-lane finishes b=2q+1, needs partner's r2. Pre-select what the
        // PARTNER needs, ONE row_ror:8 per group, then own-reg select + add.
        const float send0 = (n16 < 8) ? a0[2] : a0[1];
        const float send1 = (n16 < 8) ? a1[2] : a1[1];
        const float recv0 = ror8(send0);
        const float recv1 = ror8(send1);
        const float s0 = ((n16 < 8) ? a0[0] : a0[3]) + recv0;
        const float s1 = ((n16 < 8) ? a1[0] : a1[3]) + recv1;
        if (j0 < HID) {
            const float v = fast_tanh(s0);
            lds_A[wb][e0_tau][e0_slot][e0_idx] = (_Float16)v;
            if (last) lds_h[b_lane][j0] = v;
        }
        if (g1_on) {
            const float v = fast_tanh(s1);
            lds_A[wb][e1_tau][e1_slot][e1_idx] = (_Float16)v;
            if (last) lds_h[b_lane][j1] = v;
        }
    };

    // ================= time loop, 2 steps/iter (static reg slots) =========
    // even step t:  commit slot A (x[t+1]) -> buf1, refill A with x[t+3]
    // odd step t+1: commit slot B (x[t+2]) -> buf0, refill B with x[t+4]
    // lds_barrier drains LDS only: wave 15's x-loads stay in flight across
    // barriers; commitX's register use gets a counted vmcnt wait (free).
    #pragma unroll 1
    for (int t = 0; t < T_STEPS; t += 2) {
        lds_barrier();
        if (wv == 15 && lane < 32) {
            commitX(sA0, sA1, 1);
            const int tn = (t+3 < T_STEPS) ? (t+3) : (T_STEPS-1);
            issueLd(tn, sA0, sA1);
        }
        computeStep(0, 1, false);

        lds_barrier();
        if (wv == 15 && lane < 32) {
            commitX(sB0, sB1, 0);
            const int tn = (t+4 < T_STEPS) ? (t+4) : (T_STEPS-1);
            issueLd(tn, sB0, sB1);
        }
        computeStep(1, 0, (t + 2) == T_STEPS);
    }

    __syncthreads();   // full barrier: lds_h published

    // ---- output: out[b][o] = sum_k h[b][k]*A[o][k] + c[o] (tiny, scalar) ----
    if (tid < BB * OUT_DIM) {
        const int r = tid / OUT_DIM;
        const int o = tid % OUT_DIM;
        float s = cvec[o];
        for (int k = 0; k < HID; ++k) s += lds_h[r][k] * A[o*HID + k];
        out[(size_t)(b0 + r) * OUT_DIM + o] = s;
    }
}

extern "C" void kernel_launch(void* const* d_in, const int* in_sizes, int n_in,
                              void* d_out, int out_size, void* d_ws, size_t ws_size,
                              hipStream_t stream) {
    const float* x  = (const float*)d_in[0];
    const float* H  = (const float*)d_in[1];
    const float* U  = (const float*)d_in[2];
    const float* A  = (const float*)d_in[3];
    const float* b  = (const float*)d_in[4];
    const float* c  = (const float*)d_in[5];
    float* out = (float*)d_out;

    rnn_kernel<<<dim3(BATCH / BB), dim3(NTHREADS), 0, stream>>>(x, H, U, A, b, c, out);
}